// Round 1
// baseline (178.888 us; speedup 1.0000x reference)
//
#include <hip/hip_runtime.h>
#include <stdint.h>

#define B_ROWS 4096
#define OUTF   1024
#define INF    1024
#define KTOT   3072          // 3 * 1024
#define BN_EPS 1e-5f

typedef short  short8  __attribute__((ext_vector_type(8)));
typedef float  floatx4 __attribute__((ext_vector_type(4)));

struct alignas(8) s4 { short x, y, z, w; };

__device__ __forceinline__ short f2bf(float f) {
  union { float f; uint32_t u; } cv; cv.f = f;
  uint32_t u = cv.u;
  uint32_t r = (u + 0x7fffu + ((u >> 16) & 1u)) >> 16;  // RNE
  return (short)r;
}

__device__ __forceinline__ void load_lds16(const void* g, void* l) {
  __builtin_amdgcn_global_load_lds(
      (const __attribute__((address_space(1))) uint32_t*)(uintptr_t)g,
      (__attribute__((address_space(3))) uint32_t*)(uint32_t)(uintptr_t)l,
      16, 0, 0);
}

// ---- 1. x -> bf16 {x, x^2, x^3} packed as Xb[4096][3072] -------------------
__global__ void prep_x(const float4* __restrict__ x4, short* __restrict__ Xb) {
  int idx = blockIdx.x * blockDim.x + threadIdx.x;   // 1,048,576 float4
  float4 v = x4[idx];
  int row = idx >> 8;            // 256 float4 per row of 1024
  int c   = (idx & 255) << 2;
  size_t base = (size_t)row * KTOT + c;
  s4 p1 = { f2bf(v.x), f2bf(v.y), f2bf(v.z), f2bf(v.w) };
  float ax = v.x * v.x, ay = v.y * v.y, az = v.z * v.z, aw = v.w * v.w;
  s4 p2 = { f2bf(ax), f2bf(ay), f2bf(az), f2bf(aw) };
  s4 p3 = { f2bf(ax * v.x), f2bf(ay * v.y), f2bf(az * v.z), f2bf(aw * v.w) };
  *(s4*)&Xb[base]        = p1;
  *(s4*)&Xb[base + 1024] = p2;
  *(s4*)&Xb[base + 2048] = p3;
}

// ---- 2. c1|c2|c3 -> bf16 Wb[1024][3072] ------------------------------------
__global__ void prep_w(const float4* __restrict__ c1, const float4* __restrict__ c2,
                       const float4* __restrict__ c3, short* __restrict__ Wb) {
  int idx = blockIdx.x * blockDim.x + threadIdx.x;   // 262,144 float4
  int row = idx >> 8;
  int c   = (idx & 255) << 2;
  size_t base = (size_t)row * KTOT + c;
  float4 a = c1[idx], b = c2[idx], d = c3[idx];
  s4 p1 = { f2bf(a.x), f2bf(a.y), f2bf(a.z), f2bf(a.w) };
  s4 p2 = { f2bf(b.x), f2bf(b.y), f2bf(b.z), f2bf(b.w) };
  s4 p3 = { f2bf(d.x), f2bf(d.y), f2bf(d.z), f2bf(d.w) };
  *(s4*)&Wb[base]        = p1;
  *(s4*)&Wb[base + 1024] = p2;
  *(s4*)&Wb[base + 2048] = p3;
}

// ---- 3. biassum[o] = sum_i bias[o][i] --------------------------------------
__global__ void bias_rowsum(const float* __restrict__ bias, float* __restrict__ biassum) {
  int o = blockIdx.x;
  int t = threadIdx.x;      // 256
  float s = 0.f;
  for (int i = t; i < INF; i += 256) s += bias[(size_t)o * INF + i];
  #pragma unroll
  for (int off = 32; off > 0; off >>= 1) s += __shfl_down(s, off, 64);
  __shared__ float red[4];
  if ((t & 63) == 0) red[t >> 6] = s;
  __syncthreads();
  if (t == 0) biassum[o] = red[0] + red[1] + red[2] + red[3];
}

// ---- 4. GEMM: Y[4096][1024] = Xb * Wb^T + biassum --------------------------
__global__ __launch_bounds__(256) void gemm_poly(
    const short* __restrict__ Xb, const short* __restrict__ Wb,
    const float* __restrict__ biassum, float* __restrict__ Y) {
  __shared__ __align__(16) short As[128 * 32];
  __shared__ __align__(16) short Bs[128 * 32];
  const int tid  = threadIdx.x;
  const int lane = tid & 63;
  const int wave = tid >> 6;
  const int wr = wave >> 1;     // 2x2 wave grid, each wave 64x64
  const int wc = wave & 1;
  const int row0 = blockIdx.y * 128;
  const int col0 = blockIdx.x * 128;
  const short* Ag = Xb + (size_t)row0 * KTOT;
  const short* Bg = Wb + (size_t)col0 * KTOT;
  const int frag_m = lane & 15;
  const int frag_k = (lane >> 4) << 3;
  floatx4 acc[4][4] = {};

  for (int kt = 0; kt < KTOT; kt += 32) {
    #pragma unroll
    for (int i = 0; i < 2; ++i) {
      int c  = i * 256 + tid;     // 512 16B-chunks per 128x32 tile
      int r  = c >> 2;            // 4 chunks per 32-elem row
      int co = (c & 3) << 3;
      load_lds16(Ag + (size_t)r * KTOT + kt + co, &As[c * 8]);
      load_lds16(Bg + (size_t)r * KTOT + kt + co, &Bs[c * 8]);
    }
    __syncthreads();              // drains vmcnt (global_load_lds) + barrier
    short8 af[4], bfr[4];
    #pragma unroll
    for (int i = 0; i < 4; ++i)
      af[i] = *(const short8*)&As[(wr * 64 + i * 16 + frag_m) * 32 + frag_k];
    #pragma unroll
    for (int j = 0; j < 4; ++j)
      bfr[j] = *(const short8*)&Bs[(wc * 64 + j * 16 + frag_m) * 32 + frag_k];
    #pragma unroll
    for (int i = 0; i < 4; ++i)
      #pragma unroll
      for (int j = 0; j < 4; ++j)
        acc[i][j] = __builtin_amdgcn_mfma_f32_16x16x32_bf16(af[i], bfr[j], acc[i][j], 0, 0, 0);
    __syncthreads();              // protect LDS before next stage
  }

  const int drow = (lane >> 4) << 2;   // C/D: col=lane&15, row=(lane>>4)*4+r
  const int dcol = lane & 15;
  #pragma unroll
  for (int i = 0; i < 4; ++i) {
    #pragma unroll
    for (int j = 0; j < 4; ++j) {
      int gr = row0 + wr * 64 + i * 16 + drow;
      int gc = col0 + wc * 64 + j * 16 + dcol;
      float bsv = biassum[gc];
      #pragma unroll
      for (int r = 0; r < 4; ++r)
        Y[(size_t)(gr + r) * OUTF + gc] = acc[i][j][r] + bsv;
    }
  }
}

// ---- 5a. per-slab column sums ----------------------------------------------
__global__ void col_partial(const float* __restrict__ Y,
                            float* __restrict__ psum, float* __restrict__ psq) {
  int t = threadIdx.x;       // 1024 = one column per thread
  int p = blockIdx.x;        // 128 slabs of 32 rows
  float s = 0.f, s2 = 0.f;
  int r0 = p * 32;
  for (int r = r0; r < r0 + 32; ++r) {
    float v = Y[(size_t)r * OUTF + t];
    s += v; s2 += v * v;
  }
  psum[p * OUTF + t] = s;
  psq [p * OUTF + t] = s2;
}

// ---- 5b. finalize mean/var -> scale/shift ----------------------------------
__global__ void finalize(const float* __restrict__ psum, const float* __restrict__ psq,
                         const float* __restrict__ gamma, const float* __restrict__ beta,
                         float* __restrict__ scale, float* __restrict__ shift) {
  int t = blockIdx.x * blockDim.x + threadIdx.x;   // 1024
  float s = 0.f, s2 = 0.f;
  for (int p = 0; p < 128; ++p) { s += psum[p * OUTF + t]; s2 += psq[p * OUTF + t]; }
  float mean = s * (1.0f / B_ROWS);
  float var  = s2 * (1.0f / B_ROWS) - mean * mean;
  float sc = gamma[t] * rsqrtf(var + BN_EPS);
  scale[t] = sc;
  shift[t] = beta[t] - mean * sc;
}

// ---- 6. apply BN in place ---------------------------------------------------
__global__ void bn_apply(float* __restrict__ Y, const float* __restrict__ scale,
                         const float* __restrict__ shift) {
  int idx = blockIdx.x * blockDim.x + threadIdx.x;  // 1,048,576 float4
  float4 v = ((float4*)Y)[idx];
  int c = (idx & 255) << 2;
  v.x = v.x * scale[c]     + shift[c];
  v.y = v.y * scale[c + 1] + shift[c + 1];
  v.z = v.z * scale[c + 2] + shift[c + 2];
  v.w = v.w * scale[c + 3] + shift[c + 3];
  ((float4*)Y)[idx] = v;
}

extern "C" void kernel_launch(void* const* d_in, const int* in_sizes, int n_in,
                              void* d_out, int out_size, void* d_ws, size_t ws_size,
                              hipStream_t stream) {
  const float* x     = (const float*)d_in[0];
  const float* c1    = (const float*)d_in[1];
  const float* c2    = (const float*)d_in[2];
  const float* c3    = (const float*)d_in[3];
  const float* bias  = (const float*)d_in[4];
  const float* gamma = (const float*)d_in[5];
  const float* beta  = (const float*)d_in[6];
  float* out = (float*)d_out;
  char* ws = (char*)d_ws;

  short* Xb      = (short*)(ws);                       // 4096*3072*2 = 25,165,824
  short* Wb      = (short*)(ws + 25165824);            // 1024*3072*2 =  6,291,456
  float* biassum = (float*)(ws + 31457280);            // 4 KB
  float* psum    = (float*)(ws + 31461376);            // 128*1024*4 = 512 KB
  float* psq     = (float*)(ws + 31985664);            // 512 KB
  float* scale   = (float*)(ws + 32509952);            // 4 KB
  float* shift   = (float*)(ws + 32514048);            // 4 KB

  prep_x<<<4096, 256, 0, stream>>>((const float4*)x, Xb);
  prep_w<<<1024, 256, 0, stream>>>((const float4*)c1, (const float4*)c2,
                                   (const float4*)c3, Wb);
  bias_rowsum<<<1024, 256, 0, stream>>>(bias, biassum);

  dim3 ggrid(OUTF / 128, B_ROWS / 128);                // (8, 32)
  gemm_poly<<<ggrid, 256, 0, stream>>>(Xb, Wb, biassum, out);

  col_partial<<<128, 1024, 0, stream>>>(out, psum, psq);
  finalize<<<1, 1024, 0, stream>>>(psum, psq, gamma, beta, scale, shift);
  bn_apply<<<4096, 256, 0, stream>>>(out, scale, shift);
}

// Round 2
// 150.354 us; speedup vs baseline: 1.1898x; 1.1898x over previous
//
#include <hip/hip_runtime.h>
#include <stdint.h>

#define B_ROWS 4096
#define OUTF   1024
#define INF    1024
#define KTOT   3072          // 3 * 1024
#define BN_EPS 1e-5f
#define BM 128
#define BN 64
#define BK 32

typedef short  short8  __attribute__((ext_vector_type(8)));
typedef float  floatx4 __attribute__((ext_vector_type(4)));

struct alignas(8) s4 { short x, y, z, w; };

__device__ __forceinline__ short f2bf(float f) {
  union { float f; uint32_t u; } cv; cv.f = f;
  uint32_t u = cv.u;
  uint32_t r = (u + 0x7fffu + ((u >> 16) & 1u)) >> 16;  // RNE
  return (short)r;
}

__device__ __forceinline__ void load_lds16(const void* g, void* l) {
  __builtin_amdgcn_global_load_lds(
      (const __attribute__((address_space(1))) uint32_t*)(uintptr_t)g,
      (__attribute__((address_space(3))) uint32_t*)(uint32_t)(uintptr_t)l,
      16, 0, 0);
}

// ---- 1. fused prep: x->Xb powers, c1|c2|c3->Wb, bias rowsum ----------------
// blocks [0,4096): x    [4096,5120): w    [5120,5376): bias (4 rows/block)
__global__ void prep_all(const float4* __restrict__ x4,
                         const float4* __restrict__ c1, const float4* __restrict__ c2,
                         const float4* __restrict__ c3, const float* __restrict__ bias,
                         short* __restrict__ Xb, short* __restrict__ Wb,
                         float* __restrict__ biassum) {
  int b = blockIdx.x;
  if (b < 4096) {
    int idx = b * 256 + threadIdx.x;           // 1,048,576 float4 of x
    float4 v = x4[idx];
    int row = idx >> 8;
    int c   = (idx & 255) << 2;
    size_t base = (size_t)row * KTOT + c;
    s4 p1 = { f2bf(v.x), f2bf(v.y), f2bf(v.z), f2bf(v.w) };
    float ax = v.x * v.x, ay = v.y * v.y, az = v.z * v.z, aw = v.w * v.w;
    s4 p2 = { f2bf(ax), f2bf(ay), f2bf(az), f2bf(aw) };
    s4 p3 = { f2bf(ax * v.x), f2bf(ay * v.y), f2bf(az * v.z), f2bf(aw * v.w) };
    *(s4*)&Xb[base]        = p1;
    *(s4*)&Xb[base + 1024] = p2;
    *(s4*)&Xb[base + 2048] = p3;
  } else if (b < 5120) {
    int idx = (b - 4096) * 256 + threadIdx.x;  // 262,144 float4 per weight
    int row = idx >> 8;
    int c   = (idx & 255) << 2;
    size_t base = (size_t)row * KTOT + c;
    float4 a = c1[idx], bb = c2[idx], d = c3[idx];
    s4 p1 = { f2bf(a.x),  f2bf(a.y),  f2bf(a.z),  f2bf(a.w)  };
    s4 p2 = { f2bf(bb.x), f2bf(bb.y), f2bf(bb.z), f2bf(bb.w) };
    s4 p3 = { f2bf(d.x),  f2bf(d.y),  f2bf(d.z),  f2bf(d.w)  };
    *(s4*)&Wb[base]        = p1;
    *(s4*)&Wb[base + 1024] = p2;
    *(s4*)&Wb[base + 2048] = p3;
  } else {
    int o = (b - 5120) * 4 + (threadIdx.x >> 6);   // one wave per bias row
    int l = threadIdx.x & 63;
    const float4* bp = (const float4*)(bias + (size_t)o * INF);
    float s = 0.f;
    for (int i = l; i < 256; i += 64) { float4 v = bp[i]; s += v.x + v.y + v.z + v.w; }
    #pragma unroll
    for (int off = 32; off; off >>= 1) s += __shfl_down(s, off, 64);
    if (l == 0) biassum[o] = s;
  }
}

// ---- 2. GEMM 128x64 tiles + bias + per-block column stats ------------------
// grid (16, 32) = 512 blocks (2 blocks/CU). LDS swizzled: physical k-quarter
// q at row r holds logical quarter q ^ ((r>>1)&3)  -> 2-way-max bank aliasing.
__global__ __launch_bounds__(256, 2) void gemm_poly(
    const short* __restrict__ Xb, const short* __restrict__ Wb,
    const float* __restrict__ biassum, float* __restrict__ Y,
    float* __restrict__ psum, float* __restrict__ psq) {
  __shared__ __align__(16) short As[BM * BK];   // 8 KB
  __shared__ __align__(16) short Bs[BN * BK];   // 4 KB
  __shared__ float colred[2][2][BN];            // [wr][sum|sq][col]
  const int tid  = threadIdx.x;
  const int lane = tid & 63;
  const int wave = tid >> 6;
  const int wr = wave >> 1;      // 2 waves along M: 64 rows each
  const int wc = wave & 1;       // 2 waves along N: 32 cols each
  const int row0 = blockIdx.y * BM;
  const int col0 = blockIdx.x * BN;
  const short* Ag = Xb + (size_t)row0 * KTOT;
  const short* Bg = Wb + (size_t)col0 * KTOT;
  const int frag_m = lane & 15;
  const int sel = lane >> 4;     // logical k-quarter
  floatx4 acc[4][2] = {};

  // precompute swizzled staging coords (3 chunks/thread: A lo, A hi, B)
  const int ra0 = tid >> 2,        qa0 = tid & 3;
  const int ra1 = (256 + tid) >> 2, qa1 = tid & 3;
  const int coa0 = ((qa0 ^ ((ra0 >> 1) & 3)) << 3);
  const int coa1 = ((qa1 ^ ((ra1 >> 1) & 3)) << 3);
  const int rb = tid >> 2, qb = tid & 3;
  const int cob = ((qb ^ ((rb >> 1) & 3)) << 3);

  for (int kt = 0; kt < KTOT; kt += BK) {
    load_lds16(Ag + (size_t)ra0 * KTOT + kt + coa0, &As[tid * 8]);
    load_lds16(Ag + (size_t)ra1 * KTOT + kt + coa1, &As[(256 + tid) * 8]);
    load_lds16(Bg + (size_t)rb  * KTOT + kt + cob,  &Bs[tid * 8]);
    __syncthreads();
    short8 af[4], bfr[2];
    #pragma unroll
    for (int i = 0; i < 4; ++i) {
      int r = wr * 64 + i * 16 + frag_m;
      int qp = sel ^ ((r >> 1) & 3);
      af[i] = *(const short8*)&As[r * BK + qp * 8];
    }
    #pragma unroll
    for (int j = 0; j < 2; ++j) {
      int r = wc * 32 + j * 16 + frag_m;
      int qp = sel ^ ((r >> 1) & 3);
      bfr[j] = *(const short8*)&Bs[r * BK + qp * 8];
    }
    #pragma unroll
    for (int i = 0; i < 4; ++i)
      #pragma unroll
      for (int j = 0; j < 2; ++j)
        acc[i][j] = __builtin_amdgcn_mfma_f32_16x16x32_bf16(af[i], bfr[j], acc[i][j], 0, 0, 0);
    __syncthreads();
  }

  // epilogue: Y = acc + biassum; accumulate column sum/sumsq for BN stats
  const int drow = (lane >> 4) << 2;   // C/D: col=lane&15, row=(lane>>4)*4+r
  const int dcol = lane & 15;
  float s[2] = {0.f, 0.f}, sq[2] = {0.f, 0.f};
  #pragma unroll
  for (int j = 0; j < 2; ++j) {
    int gc = col0 + wc * 32 + j * 16 + dcol;
    float bsv = biassum[gc];
    #pragma unroll
    for (int i = 0; i < 4; ++i) {
      int gr = row0 + wr * 64 + i * 16 + drow;
      #pragma unroll
      for (int r = 0; r < 4; ++r) {
        float v = acc[i][j][r] + bsv;
        Y[(size_t)(gr + r) * OUTF + gc] = v;
        s[j] += v; sq[j] += v * v;
      }
    }
  }
  #pragma unroll
  for (int j = 0; j < 2; ++j) {       // fold the 4 lane-quads sharing a column
    s[j]  += __shfl_xor(s[j], 16, 64);  s[j]  += __shfl_xor(s[j], 32, 64);
    sq[j] += __shfl_xor(sq[j], 16, 64); sq[j] += __shfl_xor(sq[j], 32, 64);
  }
  if (sel == 0) {                      // lanes 0..15 hold the reduced values
    #pragma unroll
    for (int j = 0; j < 2; ++j) {
      int cc = wc * 32 + j * 16 + dcol;
      colred[wr][0][cc] = s[j];
      colred[wr][1][cc] = sq[j];
    }
  }
  __syncthreads();
  if (tid < BN) {
    float ssum = colred[0][0][tid] + colred[1][0][tid];
    float ssq  = colred[0][1][tid] + colred[1][1][tid];
    psum[(size_t)blockIdx.y * OUTF + col0 + tid] = ssum;
    psq [(size_t)blockIdx.y * OUTF + col0 + tid] = ssq;
  }
}

// ---- 3. finalize mean/var -> scale/shift (32 slabs) ------------------------
__global__ void finalize(const float* __restrict__ psum, const float* __restrict__ psq,
                         const float* __restrict__ gamma, const float* __restrict__ beta,
                         float* __restrict__ scale, float* __restrict__ shift) {
  int t = blockIdx.x * blockDim.x + threadIdx.x;   // 1024
  float s = 0.f, s2 = 0.f;
  for (int p = 0; p < 32; ++p) { s += psum[p * OUTF + t]; s2 += psq[p * OUTF + t]; }
  float mean = s * (1.0f / B_ROWS);
  float var  = s2 * (1.0f / B_ROWS) - mean * mean;
  float sc = gamma[t] * rsqrtf(var + BN_EPS);
  scale[t] = sc;
  shift[t] = beta[t] - mean * sc;
}

// ---- 4. apply BN in place ---------------------------------------------------
__global__ void bn_apply(float* __restrict__ Y, const float* __restrict__ scale,
                         const float* __restrict__ shift) {
  int idx = blockIdx.x * blockDim.x + threadIdx.x;  // 1,048,576 float4
  float4 v = ((float4*)Y)[idx];
  int c = (idx & 255) << 2;
  v.x = v.x * scale[c]     + shift[c];
  v.y = v.y * scale[c + 1] + shift[c + 1];
  v.z = v.z * scale[c + 2] + shift[c + 2];
  v.w = v.w * scale[c + 3] + shift[c + 3];
  ((float4*)Y)[idx] = v;
}

extern "C" void kernel_launch(void* const* d_in, const int* in_sizes, int n_in,
                              void* d_out, int out_size, void* d_ws, size_t ws_size,
                              hipStream_t stream) {
  const float* x     = (const float*)d_in[0];
  const float* c1    = (const float*)d_in[1];
  const float* c2    = (const float*)d_in[2];
  const float* c3    = (const float*)d_in[3];
  const float* bias  = (const float*)d_in[4];
  const float* gamma = (const float*)d_in[5];
  const float* beta  = (const float*)d_in[6];
  float* out = (float*)d_out;
  char* ws = (char*)d_ws;

  short* Xb      = (short*)(ws);                       // 25,165,824 B
  short* Wb      = (short*)(ws + 25165824);            //  6,291,456 B
  float* biassum = (float*)(ws + 31457280);            //      4 KB
  float* psum    = (float*)(ws + 31461376);            //    128 KB
  float* psq     = (float*)(ws + 31592448);            //    128 KB
  float* scale   = (float*)(ws + 31723520);            //      4 KB
  float* shift   = (float*)(ws + 31727616);            //      4 KB

  prep_all<<<5376, 256, 0, stream>>>((const float4*)x, (const float4*)c1,
                                     (const float4*)c2, (const float4*)c3,
                                     bias, Xb, Wb, biassum);

  dim3 ggrid(OUTF / BN, B_ROWS / BM);                  // (16, 32) = 512 blocks
  gemm_poly<<<ggrid, 256, 0, stream>>>(Xb, Wb, biassum, out, psum, psq);

  finalize<<<4, 256, 0, stream>>>(psum, psq, gamma, beta, scale, shift);
  bn_apply<<<4096, 256, 0, stream>>>(out, scale, shift);
}

// Round 4
// 135.968 us; speedup vs baseline: 1.3157x; 1.1058x over previous
//
#include <hip/hip_runtime.h>
#include <stdint.h>

#define B_ROWS 4096
#define OUTF   1024
#define INF    1024
#define KTOT   3072          // 3 * 1024
#define BN_EPS 1e-5f
#define BM 128
#define BN 64
#define BK 128               // 24 K-steps; big steps amortize barrier latency

typedef short  short8  __attribute__((ext_vector_type(8)));
typedef float  floatx4 __attribute__((ext_vector_type(4)));

struct alignas(8) s4 { short x, y, z, w; };

__device__ __forceinline__ short f2bf(float f) {
  union { float f; uint32_t u; } cv; cv.f = f;
  uint32_t u = cv.u;
  uint32_t r = (u + 0x7fffu + ((u >> 16) & 1u)) >> 16;  // RNE
  return (short)r;
}

__device__ __forceinline__ void load_lds16(const void* g, void* l) {
  __builtin_amdgcn_global_load_lds(
      (const __attribute__((address_space(1))) uint32_t*)(uintptr_t)g,
      (__attribute__((address_space(3))) uint32_t*)(uint32_t)(uintptr_t)l,
      16, 0, 0);
}

// ---- 1. fused prep: x->Xb powers, c1|c2|c3->Wb, bias rowsum ----------------
__global__ void prep_all(const float4* __restrict__ x4,
                         const float4* __restrict__ c1, const float4* __restrict__ c2,
                         const float4* __restrict__ c3, const float* __restrict__ bias,
                         short* __restrict__ Xb, short* __restrict__ Wb,
                         float* __restrict__ biassum) {
  int b = blockIdx.x;
  if (b < 4096) {
    int idx = b * 256 + threadIdx.x;           // 1,048,576 float4 of x
    float4 v = x4[idx];
    int row = idx >> 8;
    int c   = (idx & 255) << 2;
    size_t base = (size_t)row * KTOT + c;
    s4 p1 = { f2bf(v.x), f2bf(v.y), f2bf(v.z), f2bf(v.w) };
    float ax = v.x * v.x, ay = v.y * v.y, az = v.z * v.z, aw = v.w * v.w;
    s4 p2 = { f2bf(ax), f2bf(ay), f2bf(az), f2bf(aw) };
    s4 p3 = { f2bf(ax * v.x), f2bf(ay * v.y), f2bf(az * v.z), f2bf(aw * v.w) };
    *(s4*)&Xb[base]        = p1;
    *(s4*)&Xb[base + 1024] = p2;
    *(s4*)&Xb[base + 2048] = p3;
  } else if (b < 5120) {
    int idx = (b - 4096) * 256 + threadIdx.x;  // 262,144 float4 per weight
    int row = idx >> 8;
    int c   = (idx & 255) << 2;
    size_t base = (size_t)row * KTOT + c;
    float4 a = c1[idx], bb = c2[idx], d = c3[idx];
    s4 p1 = { f2bf(a.x),  f2bf(a.y),  f2bf(a.z),  f2bf(a.w)  };
    s4 p2 = { f2bf(bb.x), f2bf(bb.y), f2bf(bb.z), f2bf(bb.w) };
    s4 p3 = { f2bf(d.x),  f2bf(d.y),  f2bf(d.z),  f2bf(d.w)  };
    *(s4*)&Wb[base]        = p1;
    *(s4*)&Wb[base + 1024] = p2;
    *(s4*)&Wb[base + 2048] = p3;
  } else {
    int o = (b - 5120) * 4 + (threadIdx.x >> 6);   // one wave per bias row
    int l = threadIdx.x & 63;
    const float4* bp = (const float4*)(bias + (size_t)o * INF);
    float s = 0.f;
    for (int i = l; i < 256; i += 64) { float4 v = bp[i]; s += v.x + v.y + v.z + v.w; }
    #pragma unroll
    for (int off = 32; off; off >>= 1) s += __shfl_down(s, off, 64);
    if (l == 0) biassum[o] = s;
  }
}

// ---- 2. GEMM 128x64 tile, BK=128, swizzled LDS, fused bias + col stats -----
// LDS rows are 128 shorts (256 B) = 16 chunks of 16 B. Physical chunk slot p
// of row r holds LOGICAL chunk l = p ^ (r & 15) (global-source permutation;
// LDS placement itself stays contiguous because global_load_lds's LDS dest is
// wave-uniform base + lane*16). Bank group = p & 7, so a 16-row fragment read
// of one logical chunk spreads across all 8 groups at 2-way = free (m136).
__global__ __launch_bounds__(256, 2) void gemm_poly(
    const short* __restrict__ Xb, const short* __restrict__ Wb,
    const float* __restrict__ biassum, float* __restrict__ Y,
    float* __restrict__ psum, float* __restrict__ psq) {
  __shared__ __align__(16) short As[BM * BK];   // 32 KB
  __shared__ __align__(16) short Bs[BN * BK];   // 16 KB
  __shared__ float colred[2][2][BN];
  const int tid  = threadIdx.x;
  const int lane = tid & 63;
  const int wave = tid >> 6;
  const int wr = wave >> 1;      // 2 waves along M: 64 rows each
  const int wc = wave & 1;       // 2 waves along N: 32 cols each
  const int row0 = blockIdx.y * BM;
  const int col0 = blockIdx.x * BN;
  const short* Ag = Xb + (size_t)row0 * KTOT;
  const short* Bg = Wb + (size_t)col0 * KTOT;
  const int frag_m = lane & 15;
  const int sel = lane >> 4;     // k-quarter within a 32-wide sub-step
  floatx4 acc[4][2] = {};

  // staging source offsets (elements): 8 A-chunks + 4 B-chunks per thread
  // chunk id c: row r = c >> 4 (16 chunks per 128-short row), slot p = c & 15
  int aoff[8], boff[4];
  #pragma unroll
  for (int i = 0; i < 8; ++i) {
    int c = tid + i * 256;             // A chunk id in [0,2048)
    int r = c >> 4, p = c & 15;
    int l = p ^ (r & 15);
    aoff[i] = r * KTOT + l * 8;
  }
  #pragma unroll
  for (int i = 0; i < 4; ++i) {
    int c = tid + i * 256;             // B chunk id in [0,1024)
    int r = c >> 4, p = c & 15;
    int l = p ^ (r & 15);
    boff[i] = r * KTOT + l * 8;
  }

  for (int kt = 0; kt < KTOT; kt += BK) {
    #pragma unroll
    for (int i = 0; i < 8; ++i)
      load_lds16(Ag + aoff[i] + kt, &As[(tid + i * 256) * 8]);
    #pragma unroll
    for (int i = 0; i < 4; ++i)
      load_lds16(Bg + boff[i] + kt, &Bs[(tid + i * 256) * 8]);
    __syncthreads();              // drains vmcnt (global_load_lds) + barrier
    #pragma unroll
    for (int s = 0; s < 4; ++s) { // 4 sub-steps of K=32
      short8 af[4], bfr[2];
      #pragma unroll
      for (int i = 0; i < 4; ++i) {
        int r = wr * 64 + i * 16 + frag_m;
        int p = (s * 4 + sel) ^ (r & 15);
        af[i] = *(const short8*)&As[r * BK + p * 8];
      }
      #pragma unroll
      for (int j = 0; j < 2; ++j) {
        int r = wc * 32 + j * 16 + frag_m;
        int p = (s * 4 + sel) ^ (r & 15);
        bfr[j] = *(const short8*)&Bs[r * BK + p * 8];
      }
      #pragma unroll
      for (int i = 0; i < 4; ++i)
        #pragma unroll
        for (int j = 0; j < 2; ++j)
          acc[i][j] = __builtin_amdgcn_mfma_f32_16x16x32_bf16(af[i], bfr[j], acc[i][j], 0, 0, 0);
    }
    __syncthreads();
  }

  // epilogue: Y = acc + biassum; per-block column sum/sumsq for BN stats
  const int drow = (lane >> 4) << 2;   // C/D: col=lane&15, row=(lane>>4)*4+r
  const int dcol = lane & 15;
  float s[2] = {0.f, 0.f}, sq[2] = {0.f, 0.f};
  #pragma unroll
  for (int j = 0; j < 2; ++j) {
    int gc = col0 + wc * 32 + j * 16 + dcol;
    float bsv = biassum[gc];
    #pragma unroll
    for (int i = 0; i < 4; ++i) {
      int gr = row0 + wr * 64 + i * 16 + drow;
      #pragma unroll
      for (int r = 0; r < 4; ++r) {
        float v = acc[i][j][r] + bsv;
        Y[(size_t)(gr + r) * OUTF + gc] = v;
        s[j] += v; sq[j] += v * v;
      }
    }
  }
  #pragma unroll
  for (int j = 0; j < 2; ++j) {
    s[j]  += __shfl_xor(s[j], 16, 64);  s[j]  += __shfl_xor(s[j], 32, 64);
    sq[j] += __shfl_xor(sq[j], 16, 64); sq[j] += __shfl_xor(sq[j], 32, 64);
  }
  if (sel == 0) {
    #pragma unroll
    for (int j = 0; j < 2; ++j) {
      int cc = wc * 32 + j * 16 + dcol;
      colred[wr][0][cc] = s[j];
      colred[wr][1][cc] = sq[j];
    }
  }
  __syncthreads();
  if (tid < BN) {
    psum[(size_t)blockIdx.y * OUTF + col0 + tid] = colred[0][0][tid] + colred[1][0][tid];
    psq [(size_t)blockIdx.y * OUTF + col0 + tid] = colred[0][1][tid] + colred[1][1][tid];
  }
}

// ---- 3. fused finalize + BN apply ------------------------------------------
__global__ void bn_fused(const float* __restrict__ psum, const float* __restrict__ psq,
                         const float* __restrict__ gamma, const float* __restrict__ beta,
                         float* __restrict__ Y) {
  __shared__ float sc[32], sh[32];
  const int c0 = blockIdx.x * 32;
  const int t = threadIdx.x;
  if (t < 32) {
    float s = 0.f, s2 = 0.f;
    #pragma unroll 8
    for (int p = 0; p < 32; ++p) {
      s  += psum[p * OUTF + c0 + t];
      s2 += psq [p * OUTF + c0 + t];
    }
    float mean = s * (1.0f / B_ROWS);
    float var  = s2 * (1.0f / B_ROWS) - mean * mean;
    float scale = gamma[c0 + t] * rsqrtf(var + BN_EPS);
    sc[t] = scale;
    sh[t] = beta[c0 + t] - mean * scale;
  }
  __syncthreads();
  const int f4c = t & 7;          // 8 float4 per 32-col slice
  const int rr  = t >> 3;         // 32 rows per sweep
  const int row0 = blockIdx.y * 256;
  float4* Y4 = (float4*)Y;
  const int cb = f4c * 4;
  float s0 = sc[cb], s1 = sc[cb+1], s2 = sc[cb+2], s3 = sc[cb+3];
  float h0 = sh[cb], h1 = sh[cb+1], h2 = sh[cb+2], h3 = sh[cb+3];
  #pragma unroll
  for (int it = 0; it < 8; ++it) {
    int row = row0 + it * 32 + rr;
    size_t idx = (size_t)row * 256 + (c0 >> 2) + f4c;
    float4 v = Y4[idx];
    v.x = v.x * s0 + h0; v.y = v.y * s1 + h1;
    v.z = v.z * s2 + h2; v.w = v.w * s3 + h3;
    Y4[idx] = v;
  }
}

extern "C" void kernel_launch(void* const* d_in, const int* in_sizes, int n_in,
                              void* d_out, int out_size, void* d_ws, size_t ws_size,
                              hipStream_t stream) {
  const float* x     = (const float*)d_in[0];
  const float* c1    = (const float*)d_in[1];
  const float* c2    = (const float*)d_in[2];
  const float* c3    = (const float*)d_in[3];
  const float* bias  = (const float*)d_in[4];
  const float* gamma = (const float*)d_in[5];
  const float* beta  = (const float*)d_in[6];
  float* out = (float*)d_out;
  char* ws = (char*)d_ws;

  short* Xb      = (short*)(ws);                       // 25,165,824 B
  short* Wb      = (short*)(ws + 25165824);            //  6,291,456 B
  float* biassum = (float*)(ws + 31457280);            //      4 KB
  float* psum    = (float*)(ws + 31461376);            //    128 KB
  float* psq     = (float*)(ws + 31592448);            //    128 KB

  prep_all<<<5376, 256, 0, stream>>>((const float4*)x, (const float4*)c1,
                                     (const float4*)c2, (const float4*)c3,
                                     bias, Xb, Wb, biassum);

  dim3 ggrid(OUTF / BN, B_ROWS / BM);                  // (16, 32) = 512 blocks
  gemm_poly<<<ggrid, 256, 0, stream>>>(Xb, Wb, biassum, out, psum, psq);

  dim3 bgrid(OUTF / 32, B_ROWS / 256);                 // (32, 16) = 512 blocks
  bn_fused<<<bgrid, 256, 0, stream>>>(psum, psq, gamma, beta, out);
}

// Round 5
// 130.696 us; speedup vs baseline: 1.3687x; 1.0403x over previous
//
#include <hip/hip_runtime.h>
#include <stdint.h>

#define B_ROWS 4096
#define OUTF   1024
#define INF    1024
#define KTOT   3072          // 3 * 1024
#define BN_EPS 1e-5f
#define BM 128
#define BN 128
#define BK 64
#define NSTEP (KTOT / BK)    // 48

typedef short  short8  __attribute__((ext_vector_type(8)));
typedef float  floatx4 __attribute__((ext_vector_type(4)));

struct alignas(8) s4 { short x, y, z, w; };

__device__ __forceinline__ short f2bf(float f) {
  union { float f; uint32_t u; } cv; cv.f = f;
  uint32_t u = cv.u;
  uint32_t r = (u + 0x7fffu + ((u >> 16) & 1u)) >> 16;  // RNE
  return (short)r;
}

__device__ __forceinline__ void load_lds16(const void* g, void* l) {
  __builtin_amdgcn_global_load_lds(
      (const __attribute__((address_space(1))) uint32_t*)(uintptr_t)g,
      (__attribute__((address_space(3))) uint32_t*)(uint32_t)(uintptr_t)l,
      16, 0, 0);
}

// ---- 1. fused prep: x->Xb powers, c1|c2|c3->Wb, bias rowsum ----------------
__global__ void prep_all(const float4* __restrict__ x4,
                         const float4* __restrict__ c1, const float4* __restrict__ c2,
                         const float4* __restrict__ c3, const float* __restrict__ bias,
                         short* __restrict__ Xb, short* __restrict__ Wb,
                         float* __restrict__ biassum) {
  int b = blockIdx.x;
  if (b < 4096) {
    int idx = b * 256 + threadIdx.x;           // 1,048,576 float4 of x
    float4 v = x4[idx];
    int row = idx >> 8;
    int c   = (idx & 255) << 2;
    size_t base = (size_t)row * KTOT + c;
    s4 p1 = { f2bf(v.x), f2bf(v.y), f2bf(v.z), f2bf(v.w) };
    float ax = v.x * v.x, ay = v.y * v.y, az = v.z * v.z, aw = v.w * v.w;
    s4 p2 = { f2bf(ax), f2bf(ay), f2bf(az), f2bf(aw) };
    s4 p3 = { f2bf(ax * v.x), f2bf(ay * v.y), f2bf(az * v.z), f2bf(aw * v.w) };
    *(s4*)&Xb[base]        = p1;
    *(s4*)&Xb[base + 1024] = p2;
    *(s4*)&Xb[base + 2048] = p3;
  } else if (b < 5120) {
    int idx = (b - 4096) * 256 + threadIdx.x;  // 262,144 float4 per weight
    int row = idx >> 8;
    int c   = (idx & 255) << 2;
    size_t base = (size_t)row * KTOT + c;
    float4 a = c1[idx], bb = c2[idx], d = c3[idx];
    s4 p1 = { f2bf(a.x),  f2bf(a.y),  f2bf(a.z),  f2bf(a.w)  };
    s4 p2 = { f2bf(bb.x), f2bf(bb.y), f2bf(bb.z), f2bf(bb.w) };
    s4 p3 = { f2bf(d.x),  f2bf(d.y),  f2bf(d.z),  f2bf(d.w)  };
    *(s4*)&Wb[base]        = p1;
    *(s4*)&Wb[base + 1024] = p2;
    *(s4*)&Wb[base + 2048] = p3;
  } else {
    int o = (b - 5120) * 4 + (threadIdx.x >> 6);   // one wave per bias row
    int l = threadIdx.x & 63;
    const float4* bp = (const float4*)(bias + (size_t)o * INF);
    float s = 0.f;
    for (int i = l; i < 256; i += 64) { float4 v = bp[i]; s += v.x + v.y + v.z + v.w; }
    #pragma unroll
    for (int off = 32; off; off >>= 1) s += __shfl_down(s, off, 64);
    if (l == 0) biassum[o] = s;
  }
}

// ---- 2. GEMM 128x128 tile, BK=64, double-buffered LDS, XCD swizzle ---------
// Staged bytes = 8*Xb + 32*Wb = 403 MB (was 604). 512 threads, grid 256 =
// 1 block/CU; double-buffer hides the staging drain behind compute (one
// barrier per K-step; __syncthreads' vmcnt(0) drain IS the pipeline wait).
// XCD swizzle: XCD x gets row-strips 4x..4x+3 for all 8 col-blocks, so each
// A-slab is pulled past L2 once per XCD (per-step set ~384 KB << 4 MB L2).
// LDS swizzle: 8 chunks of 16B per 64-short row; physical slot p of row r
// holds logical chunk p ^ (r & 7) -> 2-way max bank aliasing (free, m136).
__global__ __launch_bounds__(512, 2) void gemm_poly(
    const short* __restrict__ Xb, const short* __restrict__ Wb,
    const float* __restrict__ biassum, float* __restrict__ Y,
    float* __restrict__ psum, float* __restrict__ psq) {
  __shared__ __align__(16) short As[2][BM * BK];   // 2 x 16 KB
  __shared__ __align__(16) short Bs[2][BN * BK];   // 2 x 16 KB  (total 64 KB)
  const int tid  = threadIdx.x;
  const int lane = tid & 63;
  const int wave = tid >> 6;
  const int wr = wave >> 2;            // 0..1 : 64-row half
  const int wc = wave & 3;             // 0..3 : 32-col quarter
  const int lb  = blockIdx.x;
  const int xcd = lb & 7;
  const int sl  = lb >> 3;             // 0..31
  const int bx  = sl & 7;              // col-block 0..7
  const int by  = xcd * 4 + (sl >> 3); // row-strip 0..31
  const int row0 = by * BM;
  const int col0 = bx * BN;
  const short* Ag = Xb + (size_t)row0 * KTOT;
  const short* Bg = Wb + (size_t)col0 * KTOT;
  const int frag_m = lane & 15;
  const int sel = lane >> 4;           // k-quarter within a K=32 sub-step
  floatx4 acc[4][2] = {};

  // staging source offsets: 2 A-chunks + 2 B-chunks per thread (1024 each)
  int off01[2];
  #pragma unroll
  for (int i = 0; i < 2; ++i) {
    int c = tid + i * 512;
    int r = c >> 3, p = c & 7;
    int lg = p ^ (r & 7);
    off01[i] = r * KTOT + lg * 8;
  }

  // prologue: stage tile 0 into buffer 0
  #pragma unroll
  for (int i = 0; i < 2; ++i) {
    load_lds16(Ag + off01[i], &As[0][(tid + i * 512) * 8]);
    load_lds16(Bg + off01[i], &Bs[0][(tid + i * 512) * 8]);
  }

  for (int step = 0; step < NSTEP; ++step) {
    __syncthreads();                   // drains cur-buffer loads (vmcnt) + sync
    const int cur = step & 1;
    if (step + 1 < NSTEP) {            // prefetch next tile into other buffer
      const int kt = (step + 1) * BK;
      const int nxt = cur ^ 1;
      #pragma unroll
      for (int i = 0; i < 2; ++i) {
        load_lds16(Ag + off01[i] + kt, &As[nxt][(tid + i * 512) * 8]);
        load_lds16(Bg + off01[i] + kt, &Bs[nxt][(tid + i * 512) * 8]);
      }
    }
    #pragma unroll
    for (int s = 0; s < 2; ++s) {      // 2 sub-steps of K=32
      short8 af[4], bfr[2];
      #pragma unroll
      for (int i = 0; i < 4; ++i) {
        int r = wr * 64 + i * 16 + frag_m;
        int p = (s * 4 + sel) ^ (r & 7);
        af[i] = *(const short8*)&As[cur][r * BK + p * 8];
      }
      #pragma unroll
      for (int j = 0; j < 2; ++j) {
        int r = wc * 32 + j * 16 + frag_m;
        int p = (s * 4 + sel) ^ (r & 7);
        bfr[j] = *(const short8*)&Bs[cur][r * BK + p * 8];
      }
      #pragma unroll
      for (int i = 0; i < 4; ++i)
        #pragma unroll
        for (int j = 0; j < 2; ++j)
          acc[i][j] = __builtin_amdgcn_mfma_f32_16x16x32_bf16(af[i], bfr[j], acc[i][j], 0, 0, 0);
    }
  }

  // epilogue: Y = acc + biassum; column sum/sumsq for BN stats.
  // colred aliased into As[0] (dead: last read was step 46; step-47 barrier
  // guarantees all waves passed it, and step 47 touches only buffer 1).
  float* colred = (float*)&As[0][0];   // [wr*256 + {0:sum,128:sq} + col]
  const int drow = sel << 2;           // C/D: col=lane&15, row=(lane>>4)*4+r
  const int dcol = frag_m;
  float sv[2] = {0.f, 0.f}, sq[2] = {0.f, 0.f};
  #pragma unroll
  for (int j = 0; j < 2; ++j) {
    int gc = col0 + wc * 32 + j * 16 + dcol;
    float bsv = biassum[gc];
    #pragma unroll
    for (int i = 0; i < 4; ++i) {
      int gr = row0 + wr * 64 + i * 16 + drow;
      #pragma unroll
      for (int r = 0; r < 4; ++r) {
        float v = acc[i][j][r] + bsv;
        Y[(size_t)(gr + r) * OUTF + gc] = v;
        sv[j] += v; sq[j] += v * v;
      }
    }
  }
  #pragma unroll
  for (int j = 0; j < 2; ++j) {        // fold 4 sel-groups sharing a column
    sv[j] += __shfl_xor(sv[j], 16, 64); sv[j] += __shfl_xor(sv[j], 32, 64);
    sq[j] += __shfl_xor(sq[j], 16, 64); sq[j] += __shfl_xor(sq[j], 32, 64);
  }
  if (sel == 0) {
    #pragma unroll
    for (int j = 0; j < 2; ++j) {
      int cc = wc * 32 + j * 16 + dcol;
      colred[wr * 256 + cc]       = sv[j];
      colred[wr * 256 + 128 + cc] = sq[j];
    }
  }
  __syncthreads();
  if (tid < BN) {
    float ssum = colred[tid]       + colred[256 + tid];
    float ssq  = colred[128 + tid] + colred[384 + tid];
    psum[(size_t)by * OUTF + col0 + tid] = ssum;
    psq [(size_t)by * OUTF + col0 + tid] = ssq;
  }
}

// ---- 3. fused finalize + BN apply ------------------------------------------
__global__ void bn_fused(const float* __restrict__ psum, const float* __restrict__ psq,
                         const float* __restrict__ gamma, const float* __restrict__ beta,
                         float* __restrict__ Y) {
  __shared__ float sc[32], sh[32];
  const int c0 = blockIdx.x * 32;
  const int t = threadIdx.x;
  if (t < 32) {
    float s = 0.f, s2 = 0.f;
    #pragma unroll 8
    for (int p = 0; p < 32; ++p) {
      s  += psum[p * OUTF + c0 + t];
      s2 += psq [p * OUTF + c0 + t];
    }
    float mean = s * (1.0f / B_ROWS);
    float var  = s2 * (1.0f / B_ROWS) - mean * mean;
    float scale = gamma[c0 + t] * rsqrtf(var + BN_EPS);
    sc[t] = scale;
    sh[t] = beta[c0 + t] - mean * scale;
  }
  __syncthreads();
  const int f4c = t & 7;          // 8 float4 per 32-col slice
  const int rr  = t >> 3;         // 32 rows per sweep
  const int row0 = blockIdx.y * 256;
  float4* Y4 = (float4*)Y;
  const int cb = f4c * 4;
  float s0 = sc[cb], s1 = sc[cb+1], s2 = sc[cb+2], s3 = sc[cb+3];
  float h0 = sh[cb], h1 = sh[cb+1], h2 = sh[cb+2], h3 = sh[cb+3];
  #pragma unroll
  for (int it = 0; it < 8; ++it) {
    int row = row0 + it * 32 + rr;
    size_t idx = (size_t)row * 256 + (c0 >> 2) + f4c;
    float4 v = Y4[idx];
    v.x = v.x * s0 + h0; v.y = v.y * s1 + h1;
    v.z = v.z * s2 + h2; v.w = v.w * s3 + h3;
    Y4[idx] = v;
  }
}

extern "C" void kernel_launch(void* const* d_in, const int* in_sizes, int n_in,
                              void* d_out, int out_size, void* d_ws, size_t ws_size,
                              hipStream_t stream) {
  const float* x     = (const float*)d_in[0];
  const float* c1    = (const float*)d_in[1];
  const float* c2    = (const float*)d_in[2];
  const float* c3    = (const float*)d_in[3];
  const float* bias  = (const float*)d_in[4];
  const float* gamma = (const float*)d_in[5];
  const float* beta  = (const float*)d_in[6];
  float* out = (float*)d_out;
  char* ws = (char*)d_ws;

  short* Xb      = (short*)(ws);                       // 25,165,824 B
  short* Wb      = (short*)(ws + 25165824);            //  6,291,456 B
  float* biassum = (float*)(ws + 31457280);            //      4 KB
  float* psum    = (float*)(ws + 31461376);            //    128 KB
  float* psq     = (float*)(ws + 31592448);            //    128 KB

  prep_all<<<5376, 256, 0, stream>>>((const float4*)x, (const float4*)c1,
                                     (const float4*)c2, (const float4*)c3,
                                     bias, Xb, Wb, biassum);

  gemm_poly<<<256, 512, 0, stream>>>(Xb, Wb, biassum, out, psum, psq);

  dim3 bgrid(OUTF / 32, B_ROWS / 256);                 // (32, 16) = 512 blocks
  bn_fused<<<bgrid, 256, 0, stream>>>(psum, psq, gamma, beta, out);
}